// Round 1
// baseline (548.650 us; speedup 1.0000x reference)
//
#include <hip/hip_runtime.h>

#define B_    256
#define N_    256
#define DIN   768
#define DOUT  300
#define DOUTP 304           // padded to 19*16
#define M_    (B_*N_)       // 65536
#define HP_ELEMS (M_*DOUT)  // 19660800
#define NEG_INF -9.0e15f

typedef _Float16 f16;
typedef __attribute__((ext_vector_type(8))) _Float16 f16x8;
typedef __attribute__((ext_vector_type(4))) _Float16 f16x4;
typedef __attribute__((ext_vector_type(4))) float    f32x4;

// ---------------- kernel 0: Wt[n][k] = f16(W[k][n]), zero-pad n>=300 -------
__global__ __launch_bounds__(256) void prep_wt(const float* __restrict__ W,
                                               f16* __restrict__ Wt) {
    int idx = blockIdx.x * 256 + threadIdx.x;      // over DOUTP*DIN
    if (idx >= DOUTP * DIN) return;
    int n = idx / DIN, k = idx - n * DIN;
    float v = (n < DOUT) ? W[k * DOUT + n] : 0.0f;
    Wt[idx] = (f16)v;
}

// ---------------- kernel 1: Wh = h@W + pos; f_src/f_dst; WhT fp16 to ws ----
// grid 1024 (64 rows/block), 256 threads (4 waves, 16 rows each)
__global__ __launch_bounds__(256, 2) void gemm1(
    const float* __restrict__ h, const f16* __restrict__ Wt,
    const int* __restrict__ positions,
    const float* __restrict__ a_src, const float* __restrict__ a_dst,
    const float* __restrict__ pos_table,
    f16* __restrict__ WhT, float* __restrict__ f_src, float* __restrict__ f_dst)
{
    __shared__ f16 Al[64 * 40];       // 64 rows x 32 k, stride 40 (2-way banks)
    __shared__ f16 Bl[DOUTP * 40];    // 304 n  x 32 k, stride 40

    const int tid  = threadIdx.x;
    const int wave = tid >> 6, lane = tid & 63;
    const int quad = lane >> 4, c = lane & 15;
    const int rowbase = blockIdx.x * 64;

    f32x4 acc[19];
#pragma unroll
    for (int t = 0; t < 19; ++t) acc[t] = (f32x4){0.f, 0.f, 0.f, 0.f};

    for (int kt = 0; kt < DIN / 32; ++kt) {
        { // stage A: 64x32 fp32 -> fp16
            int r = tid >> 2, c4 = tid & 3;
            const float4* src = (const float4*)(h + (size_t)(rowbase + r) * DIN + kt * 32);
            float4 v0 = src[c4];
            float4 v1 = src[c4 + 4];
            *(f16x4*)&Al[r * 40 + c4 * 4]      = (f16x4){(f16)v0.x, (f16)v0.y, (f16)v0.z, (f16)v0.w};
            *(f16x4*)&Al[r * 40 + 16 + c4 * 4] = (f16x4){(f16)v1.x, (f16)v1.y, (f16)v1.z, (f16)v1.w};
        }
        // stage B: 304x32 f16 from Wt (already transposed)
        for (int i = tid; i < DOUTP * 8; i += 256) {
            int n = i >> 3, j4 = i & 7;
            f16x4 u = *(const f16x4*)(Wt + (size_t)n * DIN + kt * 32 + j4 * 4);
            *(f16x4*)&Bl[n * 40 + j4 * 4] = u;
        }
        __syncthreads();
        f16x8 af = *(const f16x8*)&Al[(wave * 16 + c) * 40 + quad * 8];
#pragma unroll
        for (int t = 0; t < 19; ++t) {
            f16x8 bf = *(const f16x8*)&Bl[(t * 16 + c) * 40 + quad * 8];
            acc[t] = __builtin_amdgcn_mfma_f32_16x16x32_f16(af, bf, acc[t], 0, 0, 0);
        }
        __syncthreads();
    }

    // epilogue: rows grow0..grow0+3 (C/D layout: col=lane&15, row=quad*4+reg)
    const int grow0 = rowbase + wave * 16 + quad * 4;
    const int bidx  = rowbase >> 8;
    const int mbase = (rowbase & 255) + wave * 16 + quad * 4;

    int pos[4];
#pragma unroll
    for (int r = 0; r < 4; ++r) pos[r] = positions[grow0 + r];

    float fs[4] = {0, 0, 0, 0}, fd[4] = {0, 0, 0, 0};
#pragma unroll
    for (int t = 0; t < 19; ++t) {
        int col = t * 16 + c;
        if (col < DOUT) {
            float as = a_src[col], ad = a_dst[col];
#pragma unroll
            for (int r = 0; r < 4; ++r) {
                float v = acc[t][r] + pos_table[pos[r] * DOUT + col];
                acc[t][r] = v;
                fs[r] += v * as;
                fd[r] += v * ad;
            }
        } else {
#pragma unroll
            for (int r = 0; r < 4; ++r) acc[t][r] = 0.0f;
        }
    }
#pragma unroll
    for (int off = 1; off < 16; off <<= 1) {
#pragma unroll
        for (int r = 0; r < 4; ++r) {
            fs[r] += __shfl_xor(fs[r], off, 16);
            fd[r] += __shfl_xor(fd[r], off, 16);
        }
    }
    if (c == 0) {
        *(float4*)(f_src + grow0) = make_float4(fs[0], fs[1], fs[2], fs[3]);
        *(float4*)(f_dst + grow0) = make_float4(fd[0], fd[1], fd[2], fd[3]);
    }
    // WhT[b][col][m] fp16 (pad cols store 0)
#pragma unroll
    for (int t = 0; t < 19; ++t) {
        int col = t * 16 + c;
        f16x4 u = (f16x4){(f16)acc[t][0], (f16)acc[t][1], (f16)acc[t][2], (f16)acc[t][3]};
        *(f16x4*)(WhT + ((size_t)bidx * DOUTP + col) * N_ + mbase) = u;
    }
}

// ---------------- kernel 2: masked softmax -> attention (d_out) ------------
// grid 16384, 256 threads, one wave per row
__global__ __launch_bounds__(256) void softmax_att(
    const float* __restrict__ adj, const float* __restrict__ f_src,
    const float* __restrict__ f_dst, float* __restrict__ att)
{
    const int wave = threadIdx.x >> 6, lane = threadIdx.x & 63;
    const int row = blockIdx.x * 4 + wave;
    const int b = row >> 8;

    float fs = f_src[row];
    float4 fd4 = *(const float4*)(f_dst + b * N_ + lane * 4);
    float4 a4  = *(const float4*)(adj + (size_t)row * N_ + lane * 4);

    float e[4];
    {
        float v;
        v = fs + fd4.x; v = v >= 0.f ? v : 0.2f * v; e[0] = a4.x > 0.f ? v : NEG_INF;
        v = fs + fd4.y; v = v >= 0.f ? v : 0.2f * v; e[1] = a4.y > 0.f ? v : NEG_INF;
        v = fs + fd4.z; v = v >= 0.f ? v : 0.2f * v; e[2] = a4.z > 0.f ? v : NEG_INF;
        v = fs + fd4.w; v = v >= 0.f ? v : 0.2f * v; e[3] = a4.w > 0.f ? v : NEG_INF;
    }
    float mx = fmaxf(fmaxf(e[0], e[1]), fmaxf(e[2], e[3]));
#pragma unroll
    for (int off = 1; off < 64; off <<= 1) mx = fmaxf(mx, __shfl_xor(mx, off, 64));

    float p[4], s = 0.f;
#pragma unroll
    for (int i = 0; i < 4; ++i) { p[i] = __expf(e[i] - mx); s += p[i]; }
#pragma unroll
    for (int off = 1; off < 64; off <<= 1) s += __shfl_xor(s, off, 64);

    float inv = 1.0f / s;
    *(float4*)(att + (size_t)row * N_ + lane * 4) =
        make_float4(p[0] * inv, p[1] * inv, p[2] * inv, p[3] * inv);
}

// ---------------- kernel 3: h_prime = att @ Wh -----------------------------
// grid 1024 (64 rows/block), 256 threads
__global__ __launch_bounds__(256, 2) void gemm2(
    const float* __restrict__ att, const f16* __restrict__ WhT,
    float* __restrict__ hp)
{
    __shared__ f16 Al[64 * 40];
    __shared__ f16 Bl[DOUTP * 40];

    const int tid  = threadIdx.x;
    const int wave = tid >> 6, lane = tid & 63;
    const int quad = lane >> 4, c = lane & 15;
    const int rowbase = blockIdx.x * 64;
    const int bidx = rowbase >> 8;

    f32x4 acc[19];
#pragma unroll
    for (int t = 0; t < 19; ++t) acc[t] = (f32x4){0.f, 0.f, 0.f, 0.f};

    for (int kt = 0; kt < N_ / 32; ++kt) {
        { // stage A: att 64x32 fp32 -> fp16
            int r = tid >> 2, c4 = tid & 3;
            const float4* src = (const float4*)(att + (size_t)(rowbase + r) * N_ + kt * 32);
            float4 v0 = src[c4];
            float4 v1 = src[c4 + 4];
            *(f16x4*)&Al[r * 40 + c4 * 4]      = (f16x4){(f16)v0.x, (f16)v0.y, (f16)v0.z, (f16)v0.w};
            *(f16x4*)&Al[r * 40 + 16 + c4 * 4] = (f16x4){(f16)v1.x, (f16)v1.y, (f16)v1.z, (f16)v1.w};
        }
        // stage B: WhT[b][n][kt*32 + j]
        for (int i = tid; i < DOUTP * 8; i += 256) {
            int n = i >> 3, j4 = i & 7;
            f16x4 u = *(const f16x4*)(WhT + ((size_t)bidx * DOUTP + n) * N_ + kt * 32 + j4 * 4);
            *(f16x4*)&Bl[n * 40 + j4 * 4] = u;
        }
        __syncthreads();
        f16x8 af = *(const f16x8*)&Al[(wave * 16 + c) * 40 + quad * 8];
#pragma unroll
        for (int t = 0; t < 19; ++t) {
            f16x8 bf = *(const f16x8*)&Bl[(t * 16 + c) * 40 + quad * 8];
            acc[t] = __builtin_amdgcn_mfma_f32_16x16x32_f16(af, bf, acc[t], 0, 0, 0);
        }
        __syncthreads();
    }

    const int grow0 = rowbase + wave * 16 + quad * 4;
#pragma unroll
    for (int t = 0; t < 19; ++t) {
        int col = t * 16 + c;
        if (col < DOUT) {
#pragma unroll
            for (int r = 0; r < 4; ++r)
                hp[(size_t)(grow0 + r) * DOUT + col] = acc[t][r];
        }
    }
}

extern "C" void kernel_launch(void* const* d_in, const int* in_sizes, int n_in,
                              void* d_out, int out_size, void* d_ws, size_t ws_size,
                              hipStream_t stream)
{
    const float* h         = (const float*)d_in[0];
    const float* adj       = (const float*)d_in[1];
    const int*   positions = (const int*)d_in[2];
    const float* W         = (const float*)d_in[3];
    const float* a_src     = (const float*)d_in[4];
    const float* a_dst     = (const float*)d_in[5];
    const float* pos_table = (const float*)d_in[6];

    float* hp  = (float*)d_out;            // [65536][300]
    float* att = hp + HP_ELEMS;            // [65536][256]

    f16*   Wt    = (f16*)d_ws;                         // 304*768
    f16*   WhT   = Wt + (size_t)DOUTP * DIN;           // 256*304*256
    float* f_src = (float*)(WhT + (size_t)B_ * DOUTP * N_);
    float* f_dst = f_src + M_;

    hipLaunchKernelGGL(prep_wt,     dim3((DOUTP * DIN + 255) / 256), dim3(256), 0, stream, W, Wt);
    hipLaunchKernelGGL(gemm1,       dim3(M_ / 64),  dim3(256), 0, stream,
                       h, Wt, positions, a_src, a_dst, pos_table, WhT, f_src, f_dst);
    hipLaunchKernelGGL(softmax_att, dim3(M_ / 4),   dim3(256), 0, stream, adj, f_src, f_dst, att);
    hipLaunchKernelGGL(gemm2,       dim3(M_ / 64),  dim3(256), 0, stream, att, WhT, hp);
}

// Round 2
// 471.838 us; speedup vs baseline: 1.1628x; 1.1628x over previous
//
#include <hip/hip_runtime.h>

#define B_    256
#define N_    256
#define DIN   768
#define DOUT  300
#define DOUTP 320           // padded to 20*16
#define NT    20            // col tiles of 16
#define M_    (B_*N_)       // 65536
#define HP_ELEMS (M_*DOUT)  // 19660800
#define NEG_INF -9.0e15f

typedef _Float16 f16;
typedef __attribute__((ext_vector_type(8))) _Float16 f16x8;
typedef __attribute__((ext_vector_type(4))) _Float16 f16x4;
typedef __attribute__((ext_vector_type(4))) float    f32x4;

__device__ __forceinline__ void async_copy16(void* lds, const void* g) {
    __builtin_amdgcn_global_load_lds(
        (const __attribute__((address_space(1))) void*)g,
        (__attribute__((address_space(3))) void*)lds, 16, 0, 0);
}

// ---------------- kernel 0: Wt[n][k] = f16(W[k][n]), zero-pad n>=300 -------
__global__ __launch_bounds__(256) void prep_wt(const float* __restrict__ W,
                                               f16* __restrict__ Wt) {
    int idx = blockIdx.x * 256 + threadIdx.x;      // over DOUTP*DIN
    if (idx >= DOUTP * DIN) return;
    int n = idx / DIN, k = idx - n * DIN;
    float v = (n < DOUT) ? W[k * DOUT + n] : 0.0f;
    Wt[idx] = (f16)v;
}

// ---------------- kernel 1: Wh = h@W + pos; f_src/f_dst; WhT fp16 to ws ----
// grid 1024 (64 rows/block), 256 threads.
// Wave grid 2x2: wave = (rowhalf rh = w&1)*32 rows  x  (colhalf ch = w>>1)*160 cols.
__global__ __launch_bounds__(256, 3) void gemm1(
    const float* __restrict__ h, const f16* __restrict__ Wt,
    const int* __restrict__ positions,
    const float* __restrict__ a_src, const float* __restrict__ a_dst,
    const float* __restrict__ pos_table,
    f16* __restrict__ WhT, float* __restrict__ f_src, float* __restrict__ f_dst)
{
    __shared__ f16 Al[64 * 40];        // A: 64 rows x 32 k, stride 40 f16 (80B, 2-way banks)
    __shared__ f16 Bl[DOUTP * 32];     // B: 320 n x 32 k, contiguous 64B/row (DMA target)
    __shared__ float pfs[64][2], pfd[64][2];

    const int tid  = threadIdx.x;
    const int wave = tid >> 6, lane = tid & 63;
    const int quad = lane >> 4, c = lane & 15;
    const int rh = wave & 1;           // row half (32 rows)
    const int chf = wave >> 1;         // col half (10 tiles)
    const int rowbase = blockIdx.x * 64;

    // B DMA lane mapping: within a 1024B chunk, lane l -> row chk*16 + (l>>2),
    // k-chunk j' = (l&3) ^ ((l>>2)&3)  (XOR swizzle to break frag-read conflicts)
    const int brow = lane >> 2;
    const int bj   = (lane & 3) ^ (brow & 3);

    // A staging mapping: thread t -> row t>>2, k-chunk t&3 (8 floats -> f16x8)
    const int ar = tid >> 2, aj = tid & 3;

    f32x4 acc[2][10];
#pragma unroll
    for (int rt = 0; rt < 2; ++rt)
#pragma unroll
        for (int i = 0; i < 10; ++i) acc[rt][i] = (f32x4){0.f, 0.f, 0.f, 0.f};

    for (int kt = 0; kt < DIN / 32; ++kt) {
        // --- B: async DMA, 20 chunks of 1024B, 5 per wave ---
#pragma unroll
        for (int i = 0; i < 5; ++i) {
            int chk = wave + 4 * i;
            int n = chk * 16 + brow;
            async_copy16((char*)Bl + chk * 1024,
                         Wt + (size_t)n * DIN + kt * 32 + bj * 8);
        }
        // --- A: register convert fp32->fp16 ---
        {
            const float4* src = (const float4*)(h + (size_t)(rowbase + ar) * DIN + kt * 32 + aj * 8);
            float4 v0 = src[0], v1 = src[1];
            *(f16x8*)&Al[ar * 40 + aj * 8] =
                (f16x8){(f16)v0.x, (f16)v0.y, (f16)v0.z, (f16)v0.w,
                        (f16)v1.x, (f16)v1.y, (f16)v1.z, (f16)v1.w};
        }
        __syncthreads();

        f16x8 af0 = *(const f16x8*)&Al[(rh * 32 + c) * 40 + quad * 8];
        f16x8 af1 = *(const f16x8*)&Al[(rh * 32 + 16 + c) * 40 + quad * 8];
#pragma unroll
        for (int i = 0; i < 10; ++i) {
            int n = (chf * 10 + i) * 16 + c;
            f16x8 bf = *(const f16x8*)&Bl[n * 32 + (quad ^ (n & 3)) * 8];
            acc[0][i] = __builtin_amdgcn_mfma_f32_16x16x32_f16(af0, bf, acc[0][i], 0, 0, 0);
            acc[1][i] = __builtin_amdgcn_mfma_f32_16x16x32_f16(af1, bf, acc[1][i], 0, 0, 0);
        }
        __syncthreads();
    }

    // ---- epilogue: pos add, f_src/f_dst partials, WhT store ----
    const int bidx  = rowbase >> 8;
    const int mloc  = (rowbase & 255);

    int posr[2][4];
#pragma unroll
    for (int rt = 0; rt < 2; ++rt)
#pragma unroll
        for (int r = 0; r < 4; ++r)
            posr[rt][r] = positions[rowbase + rh * 32 + rt * 16 + quad * 4 + r];

    float fs[2][4] = {{0,0,0,0},{0,0,0,0}}, fd[2][4] = {{0,0,0,0},{0,0,0,0}};
#pragma unroll
    for (int i = 0; i < 10; ++i) {
        int col = (chf * 10 + i) * 16 + c;
        if (col < DOUT) {
            float as = a_src[col], ad = a_dst[col];
#pragma unroll
            for (int rt = 0; rt < 2; ++rt)
#pragma unroll
                for (int r = 0; r < 4; ++r) {
                    float v = acc[rt][i][r] + pos_table[posr[rt][r] * DOUT + col];
                    acc[rt][i][r] = v;
                    fs[rt][r] += v * as;
                    fd[rt][r] += v * ad;
                }
        } else {
#pragma unroll
            for (int rt = 0; rt < 2; ++rt)
#pragma unroll
                for (int r = 0; r < 4; ++r) acc[rt][i][r] = 0.0f;
        }
    }
#pragma unroll
    for (int off = 1; off < 16; off <<= 1) {
#pragma unroll
        for (int rt = 0; rt < 2; ++rt)
#pragma unroll
            for (int r = 0; r < 4; ++r) {
                fs[rt][r] += __shfl_xor(fs[rt][r], off, 16);
                fd[rt][r] += __shfl_xor(fd[rt][r], off, 16);
            }
    }
    if (c == 0) {
#pragma unroll
        for (int rt = 0; rt < 2; ++rt)
#pragma unroll
            for (int r = 0; r < 4; ++r) {
                int row = rh * 32 + rt * 16 + quad * 4 + r;
                pfs[row][chf] = fs[rt][r];
                pfd[row][chf] = fd[rt][r];
            }
    }
    // WhT[b][col][m] fp16
#pragma unroll
    for (int i = 0; i < 10; ++i) {
        int col = (chf * 10 + i) * 16 + c;
#pragma unroll
        for (int rt = 0; rt < 2; ++rt) {
            int mrow = mloc + rh * 32 + rt * 16 + quad * 4;
            f16x4 u = (f16x4){(f16)acc[rt][i][0], (f16)acc[rt][i][1],
                              (f16)acc[rt][i][2], (f16)acc[rt][i][3]};
            *(f16x4*)(WhT + ((size_t)bidx * DOUTP + col) * N_ + mrow) = u;
        }
    }
    __syncthreads();
    if (tid < 64) {
        f_src[rowbase + tid] = pfs[tid][0] + pfs[tid][1];
        f_dst[rowbase + tid] = pfd[tid][0] + pfd[tid][1];
    }
}

// ---------------- kernel 2: masked softmax -> attention (d_out) ------------
__global__ __launch_bounds__(256) void softmax_att(
    const float* __restrict__ adj, const float* __restrict__ f_src,
    const float* __restrict__ f_dst, float* __restrict__ att)
{
    const int wave = threadIdx.x >> 6, lane = threadIdx.x & 63;
    const int row = blockIdx.x * 4 + wave;
    const int b = row >> 8;

    float fs = f_src[row];
    float4 fd4 = *(const float4*)(f_dst + b * N_ + lane * 4);
    float4 a4  = *(const float4*)(adj + (size_t)row * N_ + lane * 4);

    float e[4];
    {
        float v;
        v = fs + fd4.x; v = v >= 0.f ? v : 0.2f * v; e[0] = a4.x > 0.f ? v : NEG_INF;
        v = fs + fd4.y; v = v >= 0.f ? v : 0.2f * v; e[1] = a4.y > 0.f ? v : NEG_INF;
        v = fs + fd4.z; v = v >= 0.f ? v : 0.2f * v; e[2] = a4.z > 0.f ? v : NEG_INF;
        v = fs + fd4.w; v = v >= 0.f ? v : 0.2f * v; e[3] = a4.w > 0.f ? v : NEG_INF;
    }
    float mx = fmaxf(fmaxf(e[0], e[1]), fmaxf(e[2], e[3]));
#pragma unroll
    for (int off = 1; off < 64; off <<= 1) mx = fmaxf(mx, __shfl_xor(mx, off, 64));

    float p[4], s = 0.f;
#pragma unroll
    for (int i = 0; i < 4; ++i) { p[i] = __expf(e[i] - mx); s += p[i]; }
#pragma unroll
    for (int off = 1; off < 64; off <<= 1) s += __shfl_xor(s, off, 64);

    float inv = 1.0f / s;
    *(float4*)(att + (size_t)row * N_ + lane * 4) =
        make_float4(p[0] * inv, p[1] * inv, p[2] * inv, p[3] * inv);
}

// ---------------- kernel 3: h_prime = att @ Wh -----------------------------
// grid 1024 (64 rows/block), 256 threads, same structure as gemm1
__global__ __launch_bounds__(256, 3) void gemm2(
    const float* __restrict__ att, const f16* __restrict__ WhT,
    float* __restrict__ hp)
{
    __shared__ f16 Al[64 * 40];
    __shared__ f16 Bl[DOUTP * 32];

    const int tid  = threadIdx.x;
    const int wave = tid >> 6, lane = tid & 63;
    const int quad = lane >> 4, c = lane & 15;
    const int rh = wave & 1;
    const int chf = wave >> 1;
    const int rowbase = blockIdx.x * 64;
    const int bidx = rowbase >> 8;

    const int brow = lane >> 2;
    const int bj   = (lane & 3) ^ (brow & 3);
    const int ar = tid >> 2, aj = tid & 3;

    f32x4 acc[2][10];
#pragma unroll
    for (int rt = 0; rt < 2; ++rt)
#pragma unroll
        for (int i = 0; i < 10; ++i) acc[rt][i] = (f32x4){0.f, 0.f, 0.f, 0.f};

    for (int kt = 0; kt < N_ / 32; ++kt) {
#pragma unroll
        for (int i = 0; i < 5; ++i) {
            int chk = wave + 4 * i;
            int n = chk * 16 + brow;
            async_copy16((char*)Bl + chk * 1024,
                         WhT + ((size_t)bidx * DOUTP + n) * N_ + kt * 32 + bj * 8);
        }
        {
            const float4* src = (const float4*)(att + (size_t)(rowbase + ar) * N_ + kt * 32 + aj * 8);
            float4 v0 = src[0], v1 = src[1];
            *(f16x8*)&Al[ar * 40 + aj * 8] =
                (f16x8){(f16)v0.x, (f16)v0.y, (f16)v0.z, (f16)v0.w,
                        (f16)v1.x, (f16)v1.y, (f16)v1.z, (f16)v1.w};
        }
        __syncthreads();

        f16x8 af0 = *(const f16x8*)&Al[(rh * 32 + c) * 40 + quad * 8];
        f16x8 af1 = *(const f16x8*)&Al[(rh * 32 + 16 + c) * 40 + quad * 8];
#pragma unroll
        for (int i = 0; i < 10; ++i) {
            int n = (chf * 10 + i) * 16 + c;
            f16x8 bf = *(const f16x8*)&Bl[n * 32 + (quad ^ (n & 3)) * 8];
            acc[0][i] = __builtin_amdgcn_mfma_f32_16x16x32_f16(af0, bf, acc[0][i], 0, 0, 0);
            acc[1][i] = __builtin_amdgcn_mfma_f32_16x16x32_f16(af1, bf, acc[1][i], 0, 0, 0);
        }
        __syncthreads();
    }

    // epilogue: hp[row][col], col<300
#pragma unroll
    for (int i = 0; i < 10; ++i) {
        int col = (chf * 10 + i) * 16 + c;
        if (col < DOUT) {
#pragma unroll
            for (int rt = 0; rt < 2; ++rt) {
                int row0 = rowbase + rh * 32 + rt * 16 + quad * 4;
#pragma unroll
                for (int r = 0; r < 4; ++r)
                    hp[(size_t)(row0 + r) * DOUT + col] = acc[rt][i][r];
            }
        }
    }
}

extern "C" void kernel_launch(void* const* d_in, const int* in_sizes, int n_in,
                              void* d_out, int out_size, void* d_ws, size_t ws_size,
                              hipStream_t stream)
{
    const float* h         = (const float*)d_in[0];
    const float* adj       = (const float*)d_in[1];
    const int*   positions = (const int*)d_in[2];
    const float* W         = (const float*)d_in[3];
    const float* a_src     = (const float*)d_in[4];
    const float* a_dst     = (const float*)d_in[5];
    const float* pos_table = (const float*)d_in[6];

    float* hp  = (float*)d_out;            // [65536][300]
    float* att = hp + HP_ELEMS;            // [65536][256]

    f16*   Wt    = (f16*)d_ws;                         // 320*768
    f16*   WhT   = Wt + (size_t)DOUTP * DIN;           // 256*320*256
    float* f_src = (float*)(WhT + (size_t)B_ * DOUTP * N_);
    float* f_dst = f_src + M_;

    hipLaunchKernelGGL(prep_wt,     dim3((DOUTP * DIN + 255) / 256), dim3(256), 0, stream, W, Wt);
    hipLaunchKernelGGL(gemm1,       dim3(M_ / 64),  dim3(256), 0, stream,
                       h, Wt, positions, a_src, a_dst, pos_table, WhT, f_src, f_dst);
    hipLaunchKernelGGL(softmax_att, dim3(M_ / 4),   dim3(256), 0, stream, adj, f_src, f_dst, att);
    hipLaunchKernelGGL(gemm2,       dim3(M_ / 64),  dim3(256), 0, stream, att, WhT, hp);
}